// Round 7
// baseline (689.199 us; speedup 1.0000x reference)
//
#include <hip/hip_runtime.h>
#include <cstdint>

#define B_ 128
#define T_ 1024
#define D_ 256
#define U_ 48

typedef float v2f __attribute__((ext_vector_type(2)));

// Guaranteed packed fp32 add (2 IEEE adds, bit-identical to scalar v_add_f32).
__device__ __forceinline__ v2f pk_add(v2f a, v2f b) {
    v2f d;
    asm("v_pk_add_f32 %0, %1, %2" : "=v"(d) : "v"(a), "v"(b));
    return d;
}
// Guaranteed 3-input max (exact, same result as two v_max_f32).
__device__ __forceinline__ float max3f(float a, float b, float c) {
    float d;
    asm("v_max3_f32 %0, %1, %2, %3" : "=v"(d) : "v"(a), "v"(b), "v"(c));
    return d;
}

// ---------------------------------------------------------------------------
// K1: logits[row][u] = sum_d x[row][d]*kernel[d][u] + bias[u].
// (unchanged — d-blocked, K in LDS, own-line loads; 2 rows/thread halves the
// uniform K-read DS traffic per row)
// ---------------------------------------------------------------------------
__global__ __launch_bounds__(256, 1) void k_logits(const float* __restrict__ x,
                                                   const float* __restrict__ kern,
                                                   const float* __restrict__ bias,
                                                   float* __restrict__ logits) {
    __shared__ float K[D_ * U_];   // 48 KB
    __shared__ float bsh[U_];
    const int tid = threadIdx.x;
    for (int i = tid; i < D_ * U_; i += 256) K[i] = kern[i];
    if (tid < U_) bsh[tid] = bias[tid];
    __syncthreads();

    const long row0 = (long)blockIdx.x * 256 + tid;      // 0..65535
    const long row1 = row0 + (long)B_ * T_ / 2;          // +65536
    const float4* xr0 = (const float4*)(x + row0 * D_);
    const float4* xr1 = (const float4*)(x + row1 * D_);

    float a0[U_], a1[U_];
#pragma unroll
    for (int u = 0; u < U_; ++u) { a0[u] = 0.0f; a1[u] = 0.0f; }

#pragma unroll 1
    for (int blk = 0; blk < D_ / 32; ++blk) {            // 8 chunks of 128 B
        float4 xa[8], xb[8];
#pragma unroll
        for (int i = 0; i < 8; ++i) xa[i] = xr0[blk * 8 + i];  // own line
#pragma unroll
        for (int i = 0; i < 8; ++i) xb[i] = xr1[blk * 8 + i];  // own line

#pragma unroll
        for (int i = 0; i < 8; ++i) {
            const int d4 = blk * 8 + i;
            const float xc0[4] = {xa[i].x, xa[i].y, xa[i].z, xa[i].w};
            const float xc1[4] = {xb[i].x, xb[i].y, xb[i].z, xb[i].w};
#pragma unroll
            for (int c = 0; c < 4; ++c) {
                const float4* kp = (const float4*)&K[(d4 * 4 + c) * U_];
                const float s0 = xc0[c], s1 = xc1[c];
#pragma unroll
                for (int u4 = 0; u4 < U_ / 4; ++u4) {
                    float4 kv = kp[u4];
                    a0[u4*4+0] += s0 * kv.x;  a1[u4*4+0] += s1 * kv.x;
                    a0[u4*4+1] += s0 * kv.y;  a1[u4*4+1] += s1 * kv.y;
                    a0[u4*4+2] += s0 * kv.z;  a1[u4*4+2] += s1 * kv.z;
                    a0[u4*4+3] += s0 * kv.w;  a1[u4*4+3] += s1 * kv.w;
                }
            }
        }
    }

    float4* o0 = (float4*)(logits + row0 * U_);
    float4* o1 = (float4*)(logits + row1 * U_);
#pragma unroll
    for (int i = 0; i < U_ / 4; ++i) {
        float4 v0, v1;
        v0.x = a0[i*4+0] + bsh[i*4+0];  v1.x = a1[i*4+0] + bsh[i*4+0];
        v0.y = a0[i*4+1] + bsh[i*4+1];  v1.y = a1[i*4+1] + bsh[i*4+1];
        v0.z = a0[i*4+2] + bsh[i*4+2];  v1.z = a1[i*4+2] + bsh[i*4+2];
        v0.w = a0[i*4+3] + bsh[i*4+3];  v1.w = a1[i*4+3] + bsh[i*4+3];
        o0[i] = v0;
        o1[i] = v1;
    }
}

// ---------------------------------------------------------------------------
// Max-plus body (R2-measured best): 12x ds_read_b128 uniform broadcast +
// 24x v_pk_add_f32 + 24x v_max3_f32 tree 48->16->6->2->1. Candidates are a
// single IEEE add of the same operands as ref; max reassociation exact.
// ---------------------------------------------------------------------------
__device__ __forceinline__ float step_max_lds(const float4* sb, const v2f* tc2) {
    float4 s[12];
#pragma unroll
    for (int k = 0; k < 12; ++k) s[k] = sb[k];        // 12x ds_read_b128
    float cf[48];
#pragma unroll
    for (int k = 0; k < 12; ++k) {
        v2f lo, hi;
        lo.x = s[k].x; lo.y = s[k].y;
        hi.x = s[k].z; hi.y = s[k].w;
        v2f r0 = pk_add(lo, tc2[2 * k + 0]);
        v2f r1 = pk_add(hi, tc2[2 * k + 1]);
        cf[4*k+0] = r0.x; cf[4*k+1] = r0.y;
        cf[4*k+2] = r1.x; cf[4*k+3] = r1.y;
    }
    float t1[16];
#pragma unroll
    for (int i = 0; i < 16; ++i) t1[i] = max3f(cf[3*i], cf[3*i+1], cf[3*i+2]);
    float t2[6];
#pragma unroll
    for (int i = 0; i < 5; ++i) t2[i] = max3f(t1[3*i], t1[3*i+1], t1[3*i+2]);
    t2[5] = t1[15];
    const float a = max3f(t2[0], t2[1], t2[2]);
    const float b = max3f(t2[3], t2[4], t2[5]);
    return fmaxf(a, b);
}

// ---------------------------------------------------------------------------
// K2 (fused): Viterbi forward + backpointers + backtrace in one kernel.
//   wave 0: the serial chain (R2 structure; delta rows -> LDS ring, no
//           global delta store).
//   wave 1: backpointer argmax, one 32-row batch behind the chain, reading
//           the ring and writing bp rows into LDS bpl.
//   epilogue: in-block blocked-composition backtrace (R6 k_back logic),
//           tags written straight to out.
// Ring = 64 slots = two 32-row halves: chain writes half kb&1 while bp reads
// the other half; one __syncthreads per batch -> race-free by construction.
// ---------------------------------------------------------------------------
#define RING 64
#define BATCH 32

#define CHAIN_STEP(IDX, J, DOPF)                                            \
    {                                                                       \
        const float logit = pf[IDX];                                        \
        if (DOPF) pf[IDX] = lp[(J) * U_];                                   \
        const float m = step_max_lds((const float4*)(ringf + roff), tc2);   \
        state = logit + m;                                                  \
        uint32_t woff = roff + U_;                                          \
        woff = (woff >= (uint32_t)(RING * U_)) ? 0u : woff;                 \
        ringf[woff + u] = state;                                            \
        roff = woff;                                                        \
    }

#define CHAIN_GROUP8(PHI, DOPF)                                             \
    CHAIN_STEP(((PHI) + 0) & 7, 0, DOPF)                                    \
    CHAIN_STEP(((PHI) + 1) & 7, 1, DOPF)                                    \
    CHAIN_STEP(((PHI) + 2) & 7, 2, DOPF)                                    \
    CHAIN_STEP(((PHI) + 3) & 7, 3, DOPF)                                    \
    CHAIN_STEP(((PHI) + 4) & 7, 4, DOPF)                                    \
    CHAIN_STEP(((PHI) + 5) & 7, 5, DOPF)                                    \
    CHAIN_STEP(((PHI) + 6) & 7, 6, DOPF)                                    \
    CHAIN_STEP(((PHI) + 7) & 7, 7, DOPF)                                    \
    lp += 8 * U_;

__global__ __launch_bounds__(128, 1) void k_fused(const float* __restrict__ trans,
                                                  const float* __restrict__ logits,
                                                  float* __restrict__ out) {
    __shared__ float ringf[RING * U_];            // 12288 B: delta ring
    __shared__ unsigned char bpl[1024 * U_];      // 49152 B (row 1023 = identity)
    __shared__ unsigned char gmap[32 * U_];       // 1536 B
    __shared__ unsigned char eIn[32];
    __shared__ int Ash;

    const int tid = threadIdx.x;
    const int wid = tid >> 6;                     // 0 = chain, 1 = bp
    const int lane = tid & 63;
    const int b = blockIdx.x;
    const int u = (lane < U_) ? lane : (U_ - 1);

    const float* lin = logits + (long)b * T_ * U_;

    // chain-wave state
    v2f tc2[U_ / 2];
    float state = 0.0f, pf[8];
    const float* lp = lin + 9 * U_ + u;
    uint32_t roff = 0;                            // ring float-offset of row (t-1)
    // bp-wave state
    float tc[U_];

    if (wid == 0) {
#pragma unroll
        for (int v = 0; v < U_; v += 2) {
            tc2[v / 2].x = trans[v * U_ + u];
            tc2[v / 2].y = trans[(v + 1) * U_ + u];
        }
        state = lin[u];                           // delta_0
        ringf[u] = state;                         // row 0 -> slot 0 (dup benign)
#pragma unroll
        for (int i = 0; i < 8; ++i) pf[i] = lin[(1 + i) * U_ + u];  // rows 1..8

        // ---- prologue: chain batch 0, t = 1..31 (3 groups of 8 + 7) ----
        CHAIN_GROUP8(0, 1)
        CHAIN_GROUP8(0, 1)
        CHAIN_GROUP8(0, 1)
        CHAIN_STEP(0, 0, 1) CHAIN_STEP(1, 1, 1) CHAIN_STEP(2, 2, 1)
        CHAIN_STEP(3, 3, 1) CHAIN_STEP(4, 4, 1) CHAIN_STEP(5, 5, 1)
        CHAIN_STEP(6, 6, 1)
        lp += 7 * U_;
    } else {
#pragma unroll
        for (int v = 0; v < U_; ++v) tc[v] = trans[v * U_ + u];
    }
    __syncthreads();                              // batch 0 visible to bp

    // ---- main: chain batch kb (t = 32kb .. 32kb+31), bp batch kb-1 ----
#pragma unroll 1
    for (int kb = 1; kb <= 32; ++kb) {
        if (wid == 0 && kb <= 31) {
            if (kb < 31) {
                CHAIN_GROUP8(7, 1) CHAIN_GROUP8(7, 1)
                CHAIN_GROUP8(7, 1) CHAIN_GROUP8(7, 1)
            } else {                              // t = 992..1023; last group no-prefetch
                CHAIN_GROUP8(7, 1) CHAIN_GROUP8(7, 1)
                CHAIN_GROUP8(7, 1) CHAIN_GROUP8(7, 0)
            }
        }
        if (wid == 1) {
            const int kbp = kb - 1;               // 0..31
            const int r0 = kbp * BATCH;           // 0,32,...,992
            const int nr = (kbp == 31) ? (BATCH - 1) : BATCH;   // skip row 1023
            uint32_t boff = (uint32_t)((r0 & (RING - 1)) * U_);
#pragma unroll 1
            for (int i = 0; i < nr; ++i) {
                const float4* sb4 = (const float4*)(ringf + boff);
                float best = -3.4e38f;
                int bi = 0;
#pragma unroll
                for (int k = 0; k < U_ / 4; ++k) {
                    float4 s = sb4[k];            // uniform broadcast read
                    float c0 = s.x + tc[4*k+0];
                    float c1 = s.y + tc[4*k+1];
                    float c2 = s.z + tc[4*k+2];
                    float c3 = s.w + tc[4*k+3];
                    bi = (c0 > best) ? 4*k+0 : bi;  best = fmaxf(best, c0);
                    bi = (c1 > best) ? 4*k+1 : bi;  best = fmaxf(best, c1);
                    bi = (c2 > best) ? 4*k+2 : bi;  best = fmaxf(best, c2);
                    bi = (c3 > best) ? 4*k+3 : bi;  best = fmaxf(best, c3);
                }
                bpl[(r0 + i) * U_ + u] = (unsigned char)bi;   // dup benign
                boff += U_;                       // stays within the half
            }
        }
        __syncthreads();
    }

    // ---- epilogue: in-block backtrace (R6 blocked composition) ----
    if (tid < U_) bpl[1023 * U_ + tid] = (unsigned char)tid;   // identity row
    if (wid == 0) {                               // argmax of delta row 1023 (slot 63)
        float v = (lane < U_) ? ringf[(1023 & (RING - 1)) * U_ + lane] : -3.4e38f;
        int idx = (lane < U_) ? lane : 64;
#pragma unroll
        for (int off = 32; off >= 1; off >>= 1) {
            const float ov = __shfl_xor(v, off);
            const int oi = __shfl_xor(idx, off);
            if (ov > v || (ov == v && oi < idx)) { v = ov; idx = oi; }
        }
        if (lane == 0) Ash = idx;
    }
    __syncthreads();

    // Phase A: 1536 (block, entry-tag) chases, 12 per thread, interleaved.
    int ik[12], ek[12], ck[12];
#pragma unroll
    for (int k = 0; k < 12; ++k) {
        const int tau = tid + k * 128;
        ik[k] = tau / U_;                         // block 0..31
        ek[k] = tau - ik[k] * U_;                 // entry tag 0..47
        ck[k] = ek[k];
    }
#pragma unroll
    for (int h = 0; h < 32; ++h) {
#pragma unroll
        for (int k = 0; k < 12; ++k) {
            const int r = ik[k] * 32 + (31 - h);
            ck[k] = bpl[r * U_ + ck[k]];
        }
    }
#pragma unroll
    for (int k = 0; k < 12; ++k) gmap[ik[k] * U_ + ek[k]] = (unsigned char)ck[k];
    __syncthreads();

    // Phase B: serial composition over 32 block maps.
    if (tid == 0) {
        int cur = Ash;
        eIn[31] = (unsigned char)cur;
#pragma unroll 1
        for (int i = 31; i >= 1; --i) {
            cur = gmap[i * U_ + cur];
            eIn[i - 1] = (unsigned char)cur;
        }
    }
    __syncthreads();

    // Phase C: 32 parallel re-chases, tags straight to global.
    float* o = out + (long)b * T_;
    if (tid < 32) {
        int cur = eIn[tid];
#pragma unroll
        for (int h = 0; h < 32; ++h) {
            const int r = tid * 32 + (31 - h);
            cur = bpl[r * U_ + cur];
            o[r] = (float)cur;
        }
    }
}

// ---------------------------------------------------------------------------
extern "C" void kernel_launch(void* const* d_in, const int* in_sizes, int n_in,
                              void* d_out, int out_size, void* d_ws, size_t ws_size,
                              hipStream_t stream) {
    const float* x     = (const float*)d_in[0];   // (B,T,D)
    const float* kern  = (const float*)d_in[1];   // (D,U)
    const float* bias  = (const float*)d_in[2];   // (U,)
    const float* trans = (const float*)d_in[3];   // (U,U)
    float* out = (float*)d_out;                   // (B,T) fp32 tags

    float* logits = (float*)d_ws;                 // 25,165,824 B — only ws user now

    k_logits<<<(B_ * T_ / 2) / 256, 256, 0, stream>>>(x, kern, bias, logits);
    k_fused <<<B_, 128, 0, stream>>>(trans, logits, out);
}